// Round 3
// baseline (40.988 us; speedup 1.0000x reference)
//
#include <hip/hip_runtime.h>

#define NROWS 64            // rows per block (lane == row)
#define NW    16            // waves per block
#define CPW   8             // cols per wave -> 16*8 = 128 cols
#define KC    64            // dims per K-chunk
#define NCHUNK (256 / KC)

__global__ __launch_bounds__(1024, 4)
void kmad_main(const float* __restrict__ x, const float* __restrict__ coords,
               int* __restrict__ out) {
    __shared__ float4 xs[2][KC / 4][NROWS];   // 32 KB, rows XOR-swizzled by (d4&7)
    __shared__ float2 red[NW][NROWS];         // 8 KB  per-wave (m1,m2) partials
    __shared__ float  m2f[NROWS];

    const int t    = threadIdx.x;
    const int lane = t & 63;
    const int wv   = t >> 6;
    const int cb   = __builtin_amdgcn_readfirstlane(wv * CPW);  // wave's col base (SGPR)
    const int row0 = blockIdx.x * NROWS;

    // ---- per-wave sqnorms of its 8 cols (registers only) ----
    float np = 0.f;
    {
        const int c  = cb + (lane >> 3);          // 8 lanes per col
        const int dS = (lane & 7) * 32;           // each lane sums 32 dims
        const float4* cp = (const float4*)(coords + (size_t)c * 256 + dS);
        #pragma unroll
        for (int i = 0; i < 8; ++i) {
            float4 v = cp[i];
            np = fmaf(v.x, v.x, np); np = fmaf(v.y, v.y, np);
            np = fmaf(v.z, v.z, np); np = fmaf(v.w, v.w, np);
        }
        np += __shfl_xor(np, 1);
        np += __shfl_xor(np, 2);
        np += __shfl_xor(np, 4);
    }
    float nrm[CPW];
    #pragma unroll
    for (int cc = 0; cc < CPW; ++cc) nrm[cc] = __shfl(np, cc * 8);

    // ---- stage chunk 0 (coalesced; XOR-swizzled LDS so row-reads are conflict-free) ----
    const int rr = t >> 4, d4s = t & 15;   // 64 rows x 16 float4 = 1024 threads
    {
        float4 v = *(const float4*)&x[(size_t)(row0 + rr) * 256 + d4s * 4];
        xs[0][d4s][rr ^ (d4s & 7)] = v;
    }
    __syncthreads();

    float acc[CPW] = {};
    const float* cbp = coords + (size_t)cb * 256;   // uniform (SGPR) base -> s_load

    #pragma unroll 1
    for (int ch = 0; ch < NCHUNK; ++ch) {
        const int d0 = ch * KC;
        if (ch + 1 < NCHUNK) {   // prefetch next chunk into the other buffer
            float4 v = *(const float4*)&x[(size_t)(row0 + rr) * 256 + (d0 + KC) + d4s * 4];
            xs[(ch + 1) & 1][d4s][rr ^ (d4s & 7)] = v;
        }
        #pragma unroll 4
        for (int d4 = 0; d4 < KC / 4; ++d4) {
            float4 a = xs[ch & 1][d4][lane ^ (d4 & 7)];   // lane's own row, 4 dims
            #pragma unroll
            for (int cc = 0; cc < CPW; ++cc) {
                const float* bp = cbp + cc * 256 + d0 + d4 * 4;  // uniform -> s_load_dwordx4
                acc[cc] = fmaf(a.x, bp[0], acc[cc]);
                acc[cc] = fmaf(a.y, bp[1], acc[cc]);
                acc[cc] = fmaf(a.z, bp[2], acc[cc]);
                acc[cc] = fmaf(a.w, bp[3], acc[cc]);
            }
        }
        __syncthreads();
    }

    // ---- epilogue: s = acc + nrm; two-smallest over 128 cols; out = (m2 > s) ----
    float s[CPW];
    #pragma unroll
    for (int cc = 0; cc < CPW; ++cc) s[cc] = acc[cc] + nrm[cc];

    float m1 = fminf(s[0], s[1]);
    float m2 = fmaxf(s[0], s[1]);
    #pragma unroll
    for (int cc = 2; cc < CPW; ++cc) {
        float hi = fmaxf(m1, s[cc]);
        m1 = fminf(m1, s[cc]);
        m2 = fminf(m2, hi);
    }
    red[wv][lane] = make_float2(m1, m2);
    __syncthreads();

    if (t < NROWS) {
        float2 p = red[0][t];
        float am1 = p.x, am2 = p.y;
        #pragma unroll
        for (int w = 1; w < NW; ++w) {
            float2 q = red[w][t];
            float nm1 = fminf(am1, q.x);
            float nm2 = fminf(fmaxf(am1, q.x), fminf(am2, q.y));
            am1 = nm1; am2 = nm2;
        }
        m2f[t] = am2;
    }
    __syncthreads();

    const float fm2 = m2f[lane];
    int4 o0, o1;
    o0.x = fm2 > s[0]; o0.y = fm2 > s[1]; o0.z = fm2 > s[2]; o0.w = fm2 > s[3];
    o1.x = fm2 > s[4]; o1.y = fm2 > s[5]; o1.z = fm2 > s[6]; o1.w = fm2 > s[7];
    int* op = out + (size_t)(row0 + lane) * 128 + cb;
    *(int4*)op = o0;
    *(int4*)(op + 4) = o1;
}

extern "C" void kernel_launch(void* const* d_in, const int* in_sizes, int n_in,
                              void* d_out, int out_size, void* d_ws, size_t ws_size,
                              hipStream_t stream) {
    const float* x      = (const float*)d_in[0];   // (16384, 256) fp32
    const float* coords = (const float*)d_in[1];   // (128, 256)   fp32
    int* out = (int*)d_out;                        // (16384, 128) bool -> int32 0/1
    kmad_main<<<16384 / NROWS, NW * 64, 0, stream>>>(x, coords, out);
}